// Round 14
// baseline (69.683 us; speedup 1.0000x reference)
//
#include <hip/hip_runtime.h>

// CARAFE: x(8,256,64,64) fp32
//   -> conv1x1 (256->64) bf16 MFMA, K-split across 2 waves (+ Bp prep trailing) -> comp bf16 NHWC
//   -> conv3x3 (64->100) bf16 MFMA, B staged in LDS (3-step phases, 3 blk/CU) + softmax, packed mask
//   -> reassembly (merged sp rows, packed bpermute, pk_fma, nontemporal out) -> out fp32
// K=5, G=1, S=2.
// maskP layout: [nimg][h][n2(50)][w] uint, n2=2t+spq, pair=(sp=2spq, sp=2spq+1) bf16 (lo,hi).

#define CI 256

typedef __attribute__((ext_vector_type(8))) short bf16x8;
typedef __attribute__((ext_vector_type(4))) float f32x4;
typedef __attribute__((ext_vector_type(2))) float f32x2;

__device__ inline unsigned short f2bf(float f) {
    unsigned u = __float_as_uint(f);
    unsigned r = (u + 0x7FFF + ((u >> 16) & 1)) >> 16;
    return (unsigned short)r;
}

__device__ inline unsigned cvt_pk_bf16(float lo, float hi) {
    unsigned r;
    asm("v_cvt_pk_bf16_f32 %0, %1, %2" : "=v"(r) : "v"(lo), "v"(hi));
    return r;
}

__device__ inline float bf_lo(unsigned u) { return __int_as_float(u << 16); }
__device__ inline float bf_hi(unsigned u) { return __int_as_float(u & 0xffff0000u); }

// acc.lo += m.lo * s.lo ; acc.hi += m.hi * s.lo   (broadcast s.lo)
__device__ inline void pk_fma_lo(f32x2& acc, f32x2 m, f32x2 s) {
    asm("v_pk_fma_f32 %0, %1, %2, %0 op_sel_hi:[1,0,1]" : "+v"(acc) : "v"(m), "v"(s));
}
// acc.lo += m.lo * s.hi ; acc.hi += m.hi * s.hi   (broadcast s.hi)
__device__ inline void pk_fma_hi(f32x2& acc, f32x2 m, f32x2 s) {
    asm("v_pk_fma_f32 %0, %1, %2, %0 op_sel:[0,1,0] op_sel_hi:[1,1,1]" : "+v"(acc) : "v"(m), "v"(s));
}

__device__ inline void nt_store2(float* p, f32x2 v) {
    __builtin_nontemporal_store(__builtin_bit_cast(unsigned long long, v),
                                (unsigned long long*)p);
}

// ---------------- kernel 0: small prep (wA, zp only — conv1x1 reads these) ----------------
__global__ __launch_bounds__(256) void prep_small(const float* __restrict__ w_comp,
                                                  unsigned short* __restrict__ wA,
                                                  float* __restrict__ zp) {
    int i = blockIdx.x * 256 + threadIdx.x;
    if (i < 64) zp[i] = 0.f;
    if (i < 64 * 256) wA[i] = f2bf(w_comp[i]);
}

// ---------------- kernel 1: 1x1 conv via MFMA, K split across 2 waves ----------------
// Block = 128 threads (2 waves). Wave wv accumulates K-range [wv*128, wv*128+128);
// wave1 ships partials through LDS, wave0 reduces + bias + packs + stores.
// Trailing 504 blocks do Bp prep.
__global__ __launch_bounds__(128) void conv1x1_mfma(const float* __restrict__ x,
                                                    const unsigned short* __restrict__ wA,
                                                    const float* __restrict__ b_comp,
                                                    const float* __restrict__ w_enc,
                                                    unsigned short* __restrict__ comp,
                                                    unsigned short* __restrict__ Bp) {
    int tid = threadIdx.x;
    int b   = blockIdx.x;

    if (b >= 2048) {
        // Bp prep: k=g*8+j, tap=k>>6, c=k&63; Bp[g][n][j] (n<100 else 0)
        int idx = (b - 2048) * 128 + tid;   // 504*128 = 64512 = 72*112*8 exactly
        int j = idx & 7;
        int n = (idx >> 3) % 112;
        int g = idx / (112 * 8);
        int k = g * 8 + j;
        int tap = k >> 6;
        int c = k & 63;
        float v = (n < 100) ? w_enc[n * 576 + c * 9 + tap] : 0.f;
        Bp[idx] = f2bf(v);
        return;
    }

    __shared__ float red[4][64][4];
    int wv  = tid >> 6;          // 0,1
    int l   = tid & 63;
    int c16 = l & 15;
    int lq  = l >> 4;
    int bs  = (b & 7) * 256 + (b >> 3);   // bijective: 2048 = 8*256
    int P0  = bs * 16;
    int nimg = P0 >> 12;
    int hw   = P0 & 4095;

    const float* xp = x + (size_t)nimg * CI * 4096 + hw + c16;

    f32x4 acc[4];
#pragma unroll
    for (int mt = 0; mt < 4; mt++) acc[mt] = f32x4{0.f, 0.f, 0.f, 0.f};

#pragma unroll
    for (int ks = 0; ks < 4; ks++) {
        int k0 = (wv * 4 + ks) * 32 + lq * 8;
        float v[8];
#pragma unroll
        for (int j = 0; j < 8; j++) v[j] = xp[(size_t)(k0 + j) * 4096];
        bf16x8 xb;
#pragma unroll
        for (int j = 0; j < 8; j++) xb[j] = (short)f2bf(v[j]);
#pragma unroll
        for (int mt = 0; mt < 4; mt++) {
            bf16x8 wf = *(const bf16x8*)(wA + (mt * 16 + c16) * 256 + k0);
            acc[mt] = __builtin_amdgcn_mfma_f32_16x16x32_bf16(wf, xb, acc[mt], 0, 0, 0);
        }
    }

    if (wv == 1) {
#pragma unroll
        for (int mt = 0; mt < 4; mt++)
            *reinterpret_cast<f32x4*>(&red[mt][l][0]) = acc[mt];
    }
    __syncthreads();
    if (wv == 0) {
        unsigned short* cp = comp + (size_t)(P0 + c16) * 64;
#pragma unroll
        for (int mt = 0; mt < 4; mt++) {
            f32x4 part = *reinterpret_cast<const f32x4*>(&red[mt][l][0]);
            int och0 = mt * 16 + lq * 4;
            float4 bb = *reinterpret_cast<const float4*>(b_comp + och0);
            float r0 = acc[mt][0] + part[0] + bb.x;
            float r1 = acc[mt][1] + part[1] + bb.y;
            float r2 = acc[mt][2] + part[2] + bb.z;
            float r3 = acc[mt][3] + part[3] + bb.w;
            unsigned u0 = f2bf(r0) | (f2bf(r1) << 16);
            unsigned u1 = f2bf(r2) | (f2bf(r3) << 16);
            reinterpret_cast<uint2*>(cp + och0)[0] = uint2{u0, u1};
        }
    }
}

// ---------------- kernel 2: 3x3 conv, B staged in LDS (3 K-steps/phase, 3 blk/CU) ----------------
__global__ __launch_bounds__(256) void conv3x3_mfma(const unsigned short* __restrict__ comp,
                                                    const unsigned short* __restrict__ Bp,
                                                    const float* __restrict__ b_enc,
                                                    const float* __restrict__ zp,
                                                    unsigned* __restrict__ maskP) {
    __shared__ char Bs[2][3 * 7168];
    int tid = threadIdx.x;
    int wv  = tid >> 6;          // 0..3 (wave id)
    int l   = tid & 63;
    int c16 = l & 15;
    int lq  = l >> 4;
    int b   = blockIdx.x;
    int bs  = (b & 7) * 64 + (b >> 3);   // bijective: 512 = 8*64
    int nimg = bs >> 6;
    int h    = bs & 63;
    int w0   = wv * 16;

    const char* cbase = (const char*)(comp + (size_t)nimg * 4096 * 64);
    const char* zpb   = (const char*)zp;
    const char* Bpb   = (const char*)Bp;

#define STAGEPH(s0_, buf_)                                                                \
    {                                                                                     \
        const char* src_ = Bpb + (s0_)*7168 + l * 16;                                     \
        for (int inst_ = wv; inst_ < 21; inst_ += 4) {                                    \
            __builtin_amdgcn_global_load_lds(                                             \
                (const __attribute__((address_space(1))) void*)(src_ + inst_ * 1024),     \
                (__attribute__((address_space(3))) void*)(&Bs[buf_][inst_ * 1024]),       \
                16, 0, 0);                                                                \
        }                                                                                 \
    }

    f32x4 acc[7];
#pragma unroll
    for (int nt = 0; nt < 7; nt++) acc[nt] = f32x4{0.f, 0.f, 0.f, 0.f};

    const int dyt[9] = {-1, -1, -1, 0, 0, 0, 1, 1, 1};
    const int dxt[9] = {-1, 0, 1, -1, 0, 1, -1, 0, 1};

    STAGEPH(0, 0);
    __syncthreads();

#pragma unroll
    for (int ph = 0; ph < 6; ph++) {
        int s0  = ph * 3;
        int cur = ph & 1;
        if (ph < 5) STAGEPH(s0 + 3, cur ^ 1);
        for (int ss = 0; ss < 3; ss++) {
            int s = s0 + ss;
            int tap = s >> 1, half = s & 1;
            int hh = h + dyt[tap];
            int ww = w0 + c16 + dxt[tap];
            const char* ap = ((unsigned)hh < 64u && (unsigned)ww < 64u)
                                 ? cbase + (hh * 64 + ww) * 128 : zpb;
            bf16x8 a = *(const bf16x8*)(ap + lq * 16 + half * 64);

            bf16x8 bf[7];
#pragma unroll
            for (int nt = 0; nt < 7; nt++)
                bf[nt] = *(const bf16x8*)(&Bs[cur][ss * 7168 + (lq * 112 + nt * 16 + c16) * 16]);
#pragma unroll
            for (int nt = 0; nt < 7; nt++)
                acc[nt] = __builtin_amdgcn_mfma_f32_16x16x32_bf16(a, bf[nt], acc[nt], 0, 0, 0);
        }
        __syncthreads();
    }
#undef STAGEPH

    float bias[7];
#pragma unroll
    for (int nt = 0; nt < 7; nt++) {
        int n = nt * 16 + c16;
        bias[nt] = (n < 100) ? b_enc[n] : 0.f;
    }
    int nvalid = (c16 < 4) ? 7 : 6;

    unsigned* mbase = maskP + ((size_t)nimg * 64 + h) * 3200;

#pragma unroll
    for (int r = 0; r < 4; r++) {
        float v[7];
#pragma unroll
        for (int nt = 0; nt < 7; nt++) v[nt] = acc[nt][r] + bias[nt];
        float m = v[0];
#pragma unroll
        for (int nt = 1; nt < 7; nt++) if (nt < nvalid) m = fmaxf(m, v[nt]);
        m = fmaxf(m, __shfl_xor(m, 4));
        m = fmaxf(m, __shfl_xor(m, 8));
        float e[7];
        float s = 0.f;
#pragma unroll
        for (int nt = 0; nt < 7; nt++) {
            e[nt] = (nt < nvalid) ? __expf(v[nt] - m) : 0.f;
            s += e[nt];
        }
        s += __shfl_xor(s, 4);
        s += __shfl_xor(s, 8);
        float inv = 1.f / s;
        int wpix = w0 + lq * 4 + r;
#pragma unroll
        for (int nt = 0; nt < 7; nt++) {
            float mine = (nt < nvalid) ? e[nt] * inv : 0.f;
            float part = __shfl_xor(mine, 1);
            if (((c16 & 1) == 0) && (nt * 16 + c16) < 100) {
                unsigned pk = cvt_pk_bf16(mine, part);
                mbase[(nt * 8 + (c16 >> 1)) * 64 + wpix] = pk;
            }
        }
    }
}

// ---------------- kernel 3: reassembly (merged sp rows, pk_fma, nontemporal out) ----------------
__global__ __launch_bounds__(256) void reassemble(const float* __restrict__ x,
                                                  const unsigned* __restrict__ maskP,
                                                  float* __restrict__ out) {
    int lane = threadIdx.x & 63;       // = w
    int cq   = threadIdx.x >> 6;       // 0..3, wave-uniform
    int b    = blockIdx.x;
    int bs   = (b & 7) * 256 + (b >> 3);   // bijective: 2048 = 8*256
    int cgb  = bs & 3;
    int h    = (bs >> 2) & 63;
    int n    = bs >> 8;
    int c0   = cgb * 64 + cq * 16;

    const unsigned* mrow = maskP + ((size_t)n * 64 + h) * 3200 + lane;

    int   yy[5];
    float vmy[5], vmx[5];
#pragma unroll
    for (int d = 0; d < 5; d++) {
        int y  = h + d - 2;
        int xc = lane + d - 2;
        yy[d]  = min(max(y, 0), 63) * 64;
        vmy[d] = ((unsigned)y  < 64u) ? 1.f : 0.f;
        vmx[d] = ((unsigned)xc < 64u) ? 1.f : 0.f;
    }

    // msk2[2t]   = (row0col0,row0col1) * fold,  msk2[2t+1] = (row1col0,row1col1) * fold
    f32x2 msk2[50];
#pragma unroll
    for (int t = 0; t < 25; t++) {
        float f = vmy[t / 5] * vmx[t % 5];
        unsigned u0 = mrow[(2 * t + 0) * 64];
        unsigned u1 = mrow[(2 * t + 1) * 64];
        f32x2 m01, m23;
        m01.x = bf_lo(u0); m01.y = bf_hi(u0);
        m23.x = bf_lo(u1); m23.y = bf_hi(u1);
        msk2[2 * t + 0] = m01 * f;
        msk2[2 * t + 1] = m23 * f;
    }

    int idxm2 = ((lane - 2) & 63) << 2;
    int idxm1 = ((lane - 1) & 63) << 2;
    int idxp1 = ((lane + 1) & 63) << 2;
    int idxp2 = ((lane + 2) & 63) << 2;

    const float* xbase = x + ((size_t)(n * CI + c0)) * 4096 + lane;
    float*       obase = out + ((size_t)(n * CI + c0) * 128 + 2 * h) * 128 + 2 * lane;

    float ra[5], rb[5];
    unsigned pk[5];
#pragma unroll
    for (int d = 0; d < 5; d++) {
        ra[d] = xbase[yy[d]];
        rb[d] = xbase[4096 + yy[d]];
        pk[d] = cvt_pk_bf16(ra[d], rb[d]);
    }

    for (int p = 0; p < 8; p++) {
        const float* xn = xbase + (size_t)((p < 7) ? (2 * p + 2) : 0) * 4096;
        float na[5], nb[5];
#pragma unroll
        for (int d = 0; d < 5; d++) {
            na[d] = xn[yy[d]];
            nb[d] = xn[4096 + yy[d]];
        }

        f32x2 A0 = {0.f, 0.f}, A1 = {0.f, 0.f};   // rows 0,1 for channel A (cols packed)
        f32x2 B0 = {0.f, 0.f}, B1 = {0.f, 0.f};   // rows 0,1 for channel B
#pragma unroll
        for (int d = 0; d < 5; d++) {
            int pv = (int)pk[d];
            int sm2 = __builtin_amdgcn_ds_bpermute(idxm2, pv);
            int sm1 = __builtin_amdgcn_ds_bpermute(idxm1, pv);
            int sp1 = __builtin_amdgcn_ds_bpermute(idxp1, pv);
            int sp2 = __builtin_amdgcn_ds_bpermute(idxp2, pv);
            f32x2 s[5];
            s[0].x = bf_lo((unsigned)sm2); s[0].y = bf_hi((unsigned)sm2);
            s[1].x = bf_lo((unsigned)sm1); s[1].y = bf_hi((unsigned)sm1);
            s[2].x = ra[d];                s[2].y = rb[d];
            s[3].x = bf_lo((unsigned)sp1); s[3].y = bf_hi((unsigned)sp1);
            s[4].x = bf_lo((unsigned)sp2); s[4].y = bf_hi((unsigned)sp2);
            const f32x2* mk2 = msk2 + d * 10;
#pragma unroll
            for (int k = 0; k < 5; k++) {
                pk_fma_lo(A0, mk2[2 * k + 0], s[k]);   // chA: rows 0
                pk_fma_lo(A1, mk2[2 * k + 1], s[k]);   // chA: rows 1
                pk_fma_hi(B0, mk2[2 * k + 0], s[k]);   // chB: rows 0
                pk_fma_hi(B1, mk2[2 * k + 1], s[k]);   // chB: rows 1
            }
        }
        float* opa = obase + (size_t)(2 * p) * 16384;
        float* opb = opa + 16384;
        nt_store2(opa, A0);
        nt_store2(opa + 128, A1);
        nt_store2(opb, B0);
        nt_store2(opb + 128, B1);

#pragma unroll
        for (int d = 0; d < 5; d++) {
            ra[d] = na[d];
            rb[d] = nb[d];
            pk[d] = cvt_pk_bf16(na[d], nb[d]);
        }
    }
}

extern "C" void kernel_launch(void* const* d_in, const int* in_sizes, int n_in,
                              void* d_out, int out_size, void* d_ws, size_t ws_size,
                              hipStream_t stream) {
    const float* x      = (const float*)d_in[0];
    const float* w_comp = (const float*)d_in[1];
    const float* b_comp = (const float*)d_in[2];
    const float* w_enc  = (const float*)d_in[3];
    const float* b_enc  = (const float*)d_in[4];
    float* out = (float*)d_out;

    // workspace layout (bytes)
    char* ws = (char*)d_ws;
    float*          zp    = (float*)(ws + 0);                 // 256 B zeros
    unsigned short* wA    = (unsigned short*)(ws + 256);      // 32768 B
    unsigned short* Bp    = (unsigned short*)(ws + 33024);    // 129024 B
    unsigned short* comp  = (unsigned short*)(ws + 162048);   // 4 MB
    unsigned*       maskP = (unsigned*)(ws + 4356352);        // 6.55 MB
    // total ~11 MB

    prep_small<<<64, 256, 0, stream>>>(w_comp, wA, zp);
    conv1x1_mfma<<<2048 + 504, 128, 0, stream>>>(x, wA, b_comp, w_enc, comp, Bp);
    conv3x3_mfma<<<512, 256, 0, stream>>>(comp, Bp, b_enc, zp, maskP);
    reassemble<<<2048, 256, 0, stream>>>(x, maskP, out);
}